// Round 7
// baseline (214.819 us; speedup 1.0000x reference)
//
#include <hip/hip_runtime.h>
#include <hip/hip_bf16.h>

// Problem constants (from reference setup_inputs): B,H,T,D fixed.
constexpr int B = 2, H = 16, T = 2048, D = 64;
constexpr int NS = T / 16;                   // 128 strided key positions
constexpr int WAVES = 4, BLOCK = 256;        // 4 waves per block
constexpr int CHUNKS = 32;                   // q-row chunks per (b,h)  -> 1024 blocks
constexpr int ROWS_PER_BLOCK = T / CHUNKS;   // 64
constexpr int ROWS_PER_WAVE = ROWS_PER_BLOCK / WAVES; // 16
constexpr int R = 4;                         // rows per group (amortize K/V sweeps)
constexpr int GROUPS = ROWS_PER_WAVE / R;    // 4

typedef float f4 __attribute__((ext_vector_type(4)));

// Uniform-index lane broadcast: v_readlane -> SGPR (VALU, zero LDS-pipe).
__device__ __forceinline__ float rlf(float v, int l) {
    return __int_as_float(__builtin_amdgcn_readlane(__float_as_int(v), l));
}

// R6 structure + NONTEMPORAL stores (the single change this round).
// Theory: R2/R5/R6 all cluster at ~170us because L2 write-allocate fetches
// each attn line from HBM before it's overwritten (~520MB of hidden fetch).
// nt stores request streaming/no-allocate, cutting traffic ~1.13GB -> ~0.62GB.
//  - scores: lane l owns keys j=l, j=l+64; Ks XOR-swizzled b128 (conflict-free);
//    q in registers, broadcast via readlane.
//  - softmax per row; p kept in registers p0[r]/p1[r] (no p_lds).
//  - PV: lane = d; V row j read from GLOBAL (256B coalesced b32, L2-resident,
//    VMEM pipe); p broadcast via readlane. 4 rows share each V sweep.
//  - attn-store gather of p[t*16+lane/4] via __shfl.
//  - streams 4 full 8KB attn rows as nt float4 (each 64B line written once).
// No barrier in the row loop (all row state is per-wave registers).
__global__ __launch_bounds__(BLOCK, 4)
void strided_attn_kernel(const float* __restrict__ q,
                         const float* __restrict__ k,
                         const float* __restrict__ v,
                         const int*   __restrict__ mask,
                         float* __restrict__ out,
                         float* __restrict__ attn)
{
    __shared__ float4 Ks4[NS][16];         // K[16j][4c..4c+3] at Ks4[j][c ^ (j&15)]
    __shared__ int    msk[NS];

    const int blk   = blockIdx.x;
    const int bh    = blk / CHUNKS;
    const int chunk = blk % CHUNKS;
    const int b     = bh / H;

    const float* qb = q + (size_t)bh * T * D;
    const float* kb = k + (size_t)bh * T * D;
    const float* vb = v + (size_t)bh * T * D;
    const int*   mb = mask + (size_t)b * T;

    const int tid = threadIdx.x;

    // Stage strided K rows (swizzled float4): 16 lanes cover one 256B row.
    for (int i = tid; i < NS * 16; i += BLOCK) {
        const int j = i >> 4, c = i & 15;
        Ks4[j][c ^ (j & 15)] =
            *reinterpret_cast<const float4*>(kb + (size_t)(j * 16) * D + c * 4);
    }
    if (tid < NS) msk[tid] = mb[tid * 16];
    __syncthreads();   // the only block-wide barrier

    const int wave = tid >> 6, lane = tid & 63;
    const int row0 = chunk * ROWS_PER_BLOCK + wave * ROWS_PER_WAVE;
    const int j0 = lane, j1 = lane + 64;
    const int xsw = lane & 15;             // same swizzle for j0/j1
    const int m0 = msk[j0], m1 = msk[j1];

    for (int g = 0; g < GROUPS; ++g) {
        const int grow = row0 + g * R;     // 4 consecutive q-rows

        // q for 4 rows in registers: lane holds q[grow + lane/16][4*(lane%16)..+3]
        const float4 qv =
            *reinterpret_cast<const float4*>(qb + (size_t)grow * D + lane * 4);

        // ---- scores: 32 swizzled b128 Ks reads; q broadcast via readlane ----
        float s0[R] = {0.f, 0.f, 0.f, 0.f};
        float s1[R] = {0.f, 0.f, 0.f, 0.f};
        #pragma unroll
        for (int cq = 0; cq < 16; ++cq) {
            const float4 k0 = Ks4[j0][cq ^ xsw];
            const float4 k1 = Ks4[j1][cq ^ xsw];
            #pragma unroll
            for (int r = 0; r < R; ++r) {
                const int src = 16 * r + cq;          // lane holding q[r][4cq..4cq+3]
                const float qx = rlf(qv.x, src);
                const float qy = rlf(qv.y, src);
                const float qz = rlf(qv.z, src);
                const float qw = rlf(qv.w, src);
                s0[r] = fmaf(qw, k0.w, fmaf(qz, k0.z, fmaf(qy, k0.y, fmaf(qx, k0.x, s0[r]))));
                s1[r] = fmaf(qw, k1.w, fmaf(qz, k1.z, fmaf(qy, k1.y, fmaf(qx, k1.x, s1[r]))));
            }
        }

        // ---- per-row mask, diag, softmax; p kept in REGISTERS ----
        float p0[R], p1[R], pd[R];
        bool  qmod[R];
        #pragma unroll
        for (int r = 0; r < R; ++r) {
            const int qrow = grow + r;
            float a0 = s0[r] * 0.125f, a1 = s1[r] * 0.125f;
            if (m0 == 0) a0 = -1e9f;
            if (m1 == 0) a1 = -1e9f;

            // diag score: per-lane q,k from global (b32 coalesced, L1/L2-hot)
            float part = qb[(size_t)qrow * D + lane] * kb[(size_t)qrow * D + lane];
            #pragma unroll
            for (int s = 32; s > 0; s >>= 1) part += __shfl_xor(part, s, 64);
            float sd = part * 0.125f;
            qmod[r] = (qrow & 15) == 0;    // diag coincides with a strided slot
            if (mb[qrow] == 0) sd = -1e9f;

            float m = fmaxf(a0, a1);
            #pragma unroll
            for (int s = 32; s > 0; s >>= 1) m = fmaxf(m, __shfl_xor(m, s, 64));
            if (!qmod[r]) m = fmaxf(m, sd);

            const float e0 = __expf(a0 - m);   // masked -> exact 0 (underflow)
            const float e1 = __expf(a1 - m);
            const float ed = qmod[r] ? 0.f : __expf(sd - m);
            float sum = e0 + e1;
            #pragma unroll
            for (int s = 32; s > 0; s >>= 1) sum += __shfl_xor(sum, s, 64);
            sum += ed;
            const float inv = 1.f / sum;

            p0[r] = e0 * inv;
            p1[r] = e1 * inv;
            pd[r] = ed * inv;
        }

        // ---- PV: lane = d; V from GLOBAL (256B coalesced per j, L2-hot);
        //      p broadcast via readlane; 4 rows share each V sweep ----
        float acc[R];
        #pragma unroll
        for (int r = 0; r < R; ++r)
            acc[r] = pd[r] * vb[(size_t)(grow + r) * D + lane];

        #pragma unroll 16
        for (int j = 0; j < 64; ++j) {
            const float vj = vb[(size_t)(j * 16) * D + lane];
            #pragma unroll
            for (int r = 0; r < R; ++r)
                acc[r] = fmaf(rlf(p0[r], j), vj, acc[r]);
        }
        #pragma unroll 16
        for (int j = 0; j < 64; ++j) {
            const float vj = vb[(size_t)((j + 64) * 16) * D + lane];
            #pragma unroll
            for (int r = 0; r < R; ++r)
                acc[r] = fmaf(rlf(p1[r], j), vj, acc[r]);
        }

        // ---- out stores (lane = d, 256B coalesced, nontemporal) ----
        #pragma unroll
        for (int r = 0; r < R; ++r)
            __builtin_nontemporal_store(acc[r], out + ((size_t)bh * T + grow + r) * D + lane);

        // ---- attn streaming stores (nt float4, each 64B line once);
        //      p gathered via shfl: lanes with lane%4==0 need p[t*16+lane/4] ----
        #pragma unroll
        for (int r = 0; r < R; ++r) {
            const int qrow = grow + r;
            f4* arow = reinterpret_cast<f4*>(attn + ((size_t)bh * T + qrow) * (size_t)T);
            const int fq = qrow >> 2;      // float4 index containing the diagonal
            const int dc = qrow & 3;
            #pragma unroll
            for (int t = 0; t < 8; ++t) {
                const int f = t * 64 + lane;
                const int jidx = t * 16 + (lane >> 2);        // key index f>>2 for lane%4==0
                const float pg = (t < 4) ? __shfl(p0[r], jidx, 64)
                                         : __shfl(p1[r], jidx - 64, 64);
                f4 val = (f4)(0.f);
                if ((f & 3) == 0) val.x = pg;                 // k = 16*(f>>2)
                if (!qmod[r] && f == fq) {
                    if      (dc == 0) val.x = pd[r];
                    else if (dc == 1) val.y = pd[r];
                    else if (dc == 2) val.z = pd[r];
                    else              val.w = pd[r];
                }
                __builtin_nontemporal_store(val, arow + f);
            }
        }
    }
}

extern "C" void kernel_launch(void* const* d_in, const int* in_sizes, int n_in,
                              void* d_out, int out_size, void* d_ws, size_t ws_size,
                              hipStream_t stream) {
    const float* q    = (const float*)d_in[0];
    const float* k    = (const float*)d_in[1];
    const float* v    = (const float*)d_in[2];
    const int*   mask = (const int*)d_in[3];

    float* out  = (float*)d_out;
    float* attn = out + (size_t)B * H * T * D;   // tuple outputs concatenated flat

    dim3 grid(B * H * CHUNKS);   // 1024 blocks; 33.3KB LDS -> 4 blocks/CU, 16 waves/CU
    dim3 block(BLOCK);
    hipLaunchKernelGGL(strided_attn_kernel, grid, block, 0, stream,
                       q, k, v, mask, out, attn);
}

// Round 8
// 160.123 us; speedup vs baseline: 1.3416x; 1.3416x over previous
//
#include <hip/hip_runtime.h>
#include <hip/hip_bf16.h>

// Problem constants (from reference setup_inputs): B,H,T,D fixed.
constexpr int B = 2, H = 16, T = 2048, D = 64;
constexpr int NS = T / 16;                   // 128 strided key positions
constexpr int WAVES = 4, BLOCK = 256;        // 4 waves per block
constexpr int CHUNKS = 16;                   // 512 blocks = exactly 2 resident/CU
constexpr int ROWS_PER_BLOCK = T / CHUNKS;   // 128
constexpr int ROWS_PER_WAVE = ROWS_PER_BLOCK / WAVES; // 32
constexpr int R = 4;                         // rows per group
constexpr int GROUPS = ROWS_PER_WAVE / R;    // 8

// Uniform-index lane broadcast: v_readlane -> SGPR (no LDS pipe).
__device__ __forceinline__ float rlf(float v, int l) {
    return __int_as_float(__builtin_amdgcn_readlane(__float_as_int(v), l));
}

// vmcnt-decoupling build: the main loop has ZERO global loads. All global
// reads (q group-layout, diag q/k dot, diag V rows, row masks) are hoisted
// to the prologue into registers. Loop = LDS (Ks/Vs/shfl, lgkmcnt) + VALU +
// stores only -> stores never block a load's s_waitcnt vmcnt (loads/stores
// share one FIFO counter; R2-R7 all serialized each group's 33-store burst
// against the next group's loads, pinning every variant at ~170-215us).
//  - scores: lane l owns keys j=l, j=l+64; Ks XOR-swizzled b128; q broadcast
//    via readlane from qg[g] registers.
//  - diag scores precomputed in prologue: kg load + dot4 + 4-level butterfly
//    (rows 4g+lane/16), broadcast in-loop via readlane.
//  - softmax per row; p kept in registers p0[r]/p1[r].
//  - PV: lane = d; Vs b32 (2 lanes/bank = free); p via readlane; diag V from
//    vd[] registers (hoisted).
//  - attn rows streamed as regular float4 stores (nt was SLOWER, R7), p
//    gathered via __shfl. Each 64B line written exactly once.
__global__ __launch_bounds__(BLOCK, 2)
void strided_attn_kernel(const float* __restrict__ q,
                         const float* __restrict__ k,
                         const float* __restrict__ v,
                         const int*   __restrict__ mask,
                         float* __restrict__ out,
                         float* __restrict__ attn)
{
    __shared__ float4 Ks4[NS][16];         // K[16j][4c..4c+3] at Ks4[j][c ^ (j&15)]
    __shared__ float  Vs[NS * 64];         // row-major; b32 reads conflict-free
    __shared__ int    msk[NS];

    const int blk   = blockIdx.x;
    const int bh    = blk / CHUNKS;
    const int chunk = blk % CHUNKS;
    const int b     = bh / H;

    const float* qb = q + (size_t)bh * T * D;
    const float* kb = k + (size_t)bh * T * D;
    const float* vb = v + (size_t)bh * T * D;
    const int*   mb = mask + (size_t)b * T;

    const int tid = threadIdx.x;

    // ---- stage strided K (swizzled) and V; 16 lanes cover one 256B row ----
    for (int i = tid; i < NS * 16; i += BLOCK) {
        const int j = i >> 4, c = i & 15;
        Ks4[j][c ^ (j & 15)] =
            *reinterpret_cast<const float4*>(kb + (size_t)(j * 16) * D + c * 4);
        *reinterpret_cast<float4*>(Vs + j * 64 + c * 4) =
            *reinterpret_cast<const float4*>(vb + (size_t)(j * 16) * D + c * 4);
    }
    if (tid < NS) msk[tid] = mb[tid * 16];

    const int wave = tid >> 6, lane = tid & 63;
    const int row0 = chunk * ROWS_PER_BLOCK + wave * ROWS_PER_WAVE;  // %16 == 0
    const int j0 = lane, j1 = lane + 64;
    const int xsw = lane & 15;

    // ---- PROLOGUE: hoist ALL remaining global loads into registers ----
    const int mvals = (lane < ROWS_PER_WAVE) ? mb[row0 + lane] : 0;

    float4 qg[GROUPS];                 // q group layout: lane -> row grow+lane/16, dims 4*(lane%16)..
    float  sdg[GROUPS];                // diag scores, row 4g + lane/16 (pre-mask)
    #pragma unroll
    for (int g = 0; g < GROUPS; ++g) {
        const int grow = row0 + g * R;
        qg[g] = *reinterpret_cast<const float4*>(qb + (size_t)grow * D + lane * 4);
        const float4 kg = *reinterpret_cast<const float4*>(kb + (size_t)grow * D + lane * 4);
        float ds = fmaf(qg[g].w, kg.w, fmaf(qg[g].z, kg.z,
                   fmaf(qg[g].y, kg.y, qg[g].x * kg.x)));
        ds += __shfl_xor(ds, 1, 64);
        ds += __shfl_xor(ds, 2, 64);
        ds += __shfl_xor(ds, 4, 64);
        ds += __shfl_xor(ds, 8, 64);   // now lane 16r.. holds full dot of row 4g+r
        sdg[g] = ds * 0.125f;
    }
    float vd[ROWS_PER_WAVE];           // diag V rows, lane = d
    #pragma unroll
    for (int rr = 0; rr < ROWS_PER_WAVE; ++rr)
        vd[rr] = vb[(size_t)(row0 + rr) * D + lane];

    __syncthreads();                   // Ks/Vs/msk ready; also drains prologue vmem

    const int m0 = msk[j0], m1 = msk[j1];

    // ---- MAIN LOOP: LDS + VALU + stores only (no vmem loads) ----
    #pragma unroll
    for (int g = 0; g < GROUPS; ++g) {
        const int grow = row0 + g * R;

        // scores: 32 swizzled b128 Ks reads; q broadcast via readlane
        float s0[R] = {0.f, 0.f, 0.f, 0.f};
        float s1[R] = {0.f, 0.f, 0.f, 0.f};
        #pragma unroll
        for (int cq = 0; cq < 16; ++cq) {
            const float4 k0 = Ks4[j0][cq ^ xsw];
            const float4 k1 = Ks4[j1][cq ^ xsw];
            #pragma unroll
            for (int r = 0; r < R; ++r) {
                const int src = 16 * r + cq;
                const float qx = rlf(qg[g].x, src);
                const float qy = rlf(qg[g].y, src);
                const float qz = rlf(qg[g].z, src);
                const float qw = rlf(qg[g].w, src);
                s0[r] = fmaf(qw, k0.w, fmaf(qz, k0.z, fmaf(qy, k0.y, fmaf(qx, k0.x, s0[r]))));
                s1[r] = fmaf(qw, k1.w, fmaf(qz, k1.z, fmaf(qy, k1.y, fmaf(qx, k1.x, s1[r]))));
            }
        }

        // softmax per row; p kept in registers
        float p0[R], p1[R], pd[R];
        #pragma unroll
        for (int r = 0; r < R; ++r) {
            const bool qmod = (((g * R + r) & 15) == 0);   // row0 % 16 == 0
            float a0 = s0[r] * 0.125f, a1 = s1[r] * 0.125f;
            if (m0 == 0) a0 = -1e9f;
            if (m1 == 0) a1 = -1e9f;

            float sd = rlf(sdg[g], 16 * r);
            if (__builtin_amdgcn_readlane(mvals, g * R + r) == 0) sd = -1e9f;

            float m = fmaxf(a0, a1);
            #pragma unroll
            for (int s = 32; s > 0; s >>= 1) m = fmaxf(m, __shfl_xor(m, s, 64));
            if (!qmod) m = fmaxf(m, sd);

            const float e0 = __expf(a0 - m);   // masked -> exact 0 (underflow)
            const float e1 = __expf(a1 - m);
            const float ed = qmod ? 0.f : __expf(sd - m);
            float sum = e0 + e1;
            #pragma unroll
            for (int s = 32; s > 0; s >>= 1) sum += __shfl_xor(sum, s, 64);
            sum += ed;
            const float inv = 1.f / sum;

            p0[r] = e0 * inv;
            p1[r] = e1 * inv;
            pd[r] = ed * inv;
        }

        // PV: lane = d; Vs b32 shared over 4 rows; p via readlane; diag from vd[]
        float acc[R];
        #pragma unroll
        for (int r = 0; r < R; ++r)
            acc[r] = pd[r] * vd[g * R + r];

        #pragma unroll 16
        for (int j = 0; j < 64; ++j) {
            const float vj = Vs[j * 64 + lane];
            #pragma unroll
            for (int r = 0; r < R; ++r)
                acc[r] = fmaf(rlf(p0[r], j), vj, acc[r]);
        }
        #pragma unroll 16
        for (int j = 0; j < 64; ++j) {
            const float vj = Vs[(j + 64) * 64 + lane];
            #pragma unroll
            for (int r = 0; r < R; ++r)
                acc[r] = fmaf(rlf(p1[r], j), vj, acc[r]);
        }

        // out stores (lane = d, 256B coalesced)
        #pragma unroll
        for (int r = 0; r < R; ++r)
            out[((size_t)bh * T + grow + r) * D + lane] = acc[r];

        // attn streaming stores (regular float4; each 64B line once);
        // p gathered via shfl: lane%4==0 needs p[t*16 + lane/4]
        #pragma unroll
        for (int r = 0; r < R; ++r) {
            const int qrow = grow + r;
            float4* arow = reinterpret_cast<float4*>(attn + ((size_t)bh * T + qrow) * (size_t)T);
            const int fq = qrow >> 2;          // float4 index holding the diagonal
            const bool qmod = (((g * R + r) & 15) == 0);
            #pragma unroll
            for (int t = 0; t < 8; ++t) {
                const int f = t * 64 + lane;
                const int jidx = t * 16 + (lane >> 2);
                const float pg = (t < 4) ? __shfl(p0[r], jidx, 64)
                                         : __shfl(p1[r], jidx - 64, 64);
                float4 val = make_float4(0.f, 0.f, 0.f, 0.f);
                if ((f & 3) == 0) val.x = pg;  // k = 16*(f>>2)
                if (!qmod && f == fq) {        // diagonal k == qrow; dc == r
                    if      (r == 0) val.x = pd[r];
                    else if (r == 1) val.y = pd[r];
                    else if (r == 2) val.z = pd[r];
                    else             val.w = pd[r];
                }
                arow[f] = val;
            }
        }
    }
}

extern "C" void kernel_launch(void* const* d_in, const int* in_sizes, int n_in,
                              void* d_out, int out_size, void* d_ws, size_t ws_size,
                              hipStream_t stream) {
    const float* q    = (const float*)d_in[0];
    const float* k    = (const float*)d_in[1];
    const float* v    = (const float*)d_in[2];
    const int*   mask = (const int*)d_in[3];

    float* out  = (float*)d_out;
    float* attn = out + (size_t)B * H * T * D;   // tuple outputs concatenated flat

    dim3 grid(B * H * CHUNKS);   // 512 blocks; 64.5KB LDS -> 2 blocks/CU
    dim3 block(BLOCK);
    hipLaunchKernelGGL(strided_attn_kernel, grid, block, 0, stream,
                       q, k, v, mask, out, attn);
}